// Round 3
// baseline (233.042 us; speedup 1.0000x reference)
//
#include <hip/hip_runtime.h>
#include <hip/hip_bf16.h>

#define B_   64
#define T_   4096
#define F_   134     // 2K input features
#define FP_  160     // padded to 5 K-tiles of 32
#define D_   256
#define C_   7
#define THR_ 0.1f
#define EPS_ 1e-5f
#define NQ_  16      // j-groups; grid.x = NQ_*64 = 1024 blocks

typedef __bf16 bf16x8 __attribute__((ext_vector_type(8)));
typedef float  f32x4  __attribute__((ext_vector_type(4)));

typedef __attribute__((address_space(1))) const unsigned int guint;
typedef __attribute__((address_space(3))) unsigned int luint;

// FULL barrier: drain ALL own vmem (DMA) + LDS ops, then barrier.
// Invariant (the R2-bug fix): every wave drains its own global_load_lds
// BEFORE the barrier => after the barrier the staged slab is collectively
// complete. lgkm-only barrier is only legal where no DMA visibility is needed.
#define FBAR() asm volatile("s_waitcnt vmcnt(0) lgkmcnt(0)\n\ts_barrier" ::: "memory")
#define LBAR() asm volatile("s_waitcnt lgkmcnt(0)\n\ts_barrier" ::: "memory")

// ws layout:
//   [0, 65536)            pooled  f32 [64][256]   (memset to 0 each launch)
//   [65536, 65536+81920)  W1bf    bf16 [256][160] (d-major, f contiguous, padded)

// tiled transpose, both sides coalesced
__global__ void convert_w1(const float* __restrict__ W1, __bf16* __restrict__ W1bf) {
    __shared__ float tile[32][33];
    const int d0 = blockIdx.x * 32, f0 = blockIdx.y * 32;
    const int tx = threadIdx.x & 31, ty = threadIdx.x >> 5;   // ty 0..7
#pragma unroll
    for (int r = 0; r < 32; r += 8) {
        int f = f0 + ty + r;
        tile[ty + r][tx] = (f < F_) ? W1[f * D_ + d0 + tx] : 0.f;
    }
    __syncthreads();
#pragma unroll
    for (int r = 0; r < 32; r += 8) {
        int d = d0 + ty + r;
        W1bf[d * FP_ + f0 + tx] = (__bf16)tile[tx][ty + r];
    }
}

// Balanced tile assignment: block p = 64q + r owns candidates i in [0,8):
//   b = (r+i) & 63, j = q + 16i   (bijective over all (b, j<128) pairs)
// Valid iff 32j < len(b).  Tiles come from 8 DIFFERENT batch rows -> per-block
// work ~= 4 +- 1.2 tiles instead of 0..8 fully correlated.
// Pipeline per tile, ONE barrier: stage(s+2) || repack(s+1) || MFMA(s) ->
// epilogue -> [vmcnt(0)+lgkm(0)+barrier] -> atomic (flies across next iter).
__global__ __launch_bounds__(256, 2)
void fused_mlp_pool(const float* __restrict__ body,
                    const float* __restrict__ hr,
                    const float* __restrict__ hl,
                    const int*   __restrict__ length,
                    const float* __restrict__ b1,
                    const __bf16* __restrict__ W1bf,
                    float* __restrict__ pooled)
{
    const int p = blockIdx.x;
    const int q = p >> 6;           // 0..15
    const int r = p & 63;

    const int tid  = threadIdx.x;
    const int wave = tid >> 6;
    const int lane = tid & 63;
    const int quad = lane >> 4;
    const int l16  = lane & 15;
    const int dbase = wave * 64;

    // ---- candidate set (uniform scalar computation; lens packed in 2 u64) ----
    const int L1 = length[1];       // int64-stored? odd words are 0
    unsigned int mask = 0;
    unsigned long long len01 = 0, len23 = 0;
#pragma unroll
    for (int i = 0; i < 8; i++) {
        int bi = (r + i) & 63;
        int li = (L1 == 0) ? length[2 * bi] : length[bi];
        int ji = q + 16 * i;
        if (ji * 32 < li) mask |= (1u << i);
        if (i < 4) len01 |= (unsigned long long)(unsigned)li << (16 * i);
        else       len23 |= (unsigned long long)(unsigned)li << (16 * (i - 4));
    }
    const int m = __popc(mask);
    if (m == 0) return;

    __shared__ __align__(16) float  raw[2][6432];    // 2 x 25728 B raw slabs
    __shared__ __align__(16) __bf16 As2[2][5120];    // 2 x 10240 B packed A tiles

    const long rowstride = (long)T_;

    // pure-DMA staging (exec-masked tail issues; no vmcnt bookkeeping needed)
    auto stage = [&](int c, int bufi) {
        const int  bb = (r + c) & 63;
        const long t0 = (long)(q + 16 * c) * 32;
        const float* bodyt = body + (bb * rowstride + t0) * 75;   // 9600 B
        const float* hrt   = hr   + (bb * rowstride + t0) * 63;   // 8064 B
        const float* hlt   = hl   + (bb * rowstride + t0) * 63;
        char* rw = (char*)raw[bufi];
        for (int i = wave; i < 10; i += 4) {            // body: 2400 dwords
            int off = i * 256 + lane * 4;
            if (off < 2400)
                __builtin_amdgcn_global_load_lds((guint*)(bodyt + off),
                                                 (luint*)(rw + off * 4), 16, 0, 0);
        }
        for (int i = wave; i < 8; i += 4) {             // hr+hl: 2016 dwords each
            int off = i * 256 + lane * 4;
            if (off < 2016) {
                __builtin_amdgcn_global_load_lds((guint*)(hrt + off),
                                                 (luint*)(rw + 9600 + off * 4), 16, 0, 0);
                __builtin_amdgcn_global_load_lds((guint*)(hlt + off),
                                                 (luint*)(rw + 17664 + off * 4), 16, 0, 0);
            }
        }
    };

    // nth valid candidate (uniform scalar)
    auto nth = [&](int n) -> int {
        unsigned int t = mask;
        for (int k = 0; k < n; k++) t &= t - 1;
        return __ffs(t) - 1;
    };

    // ---- prologue: kick off first two tiles' DMA as early as possible ----
    int cs  = nth(0);
    int cs1 = (m > 1) ? nth(1) : -1;
    stage(cs, 0);
    if (m > 1) stage(cs1, 1);

    // B fragments + bias: once per block (overlaps the DMA; drained by FBAR)
    bf16x8 bfrag[4][5];
    float  b1v[4];
#pragma unroll
    for (int n = 0; n < 4; n++) {
        int d = dbase + n * 16 + l16;
        const __bf16* wp = W1bf + d * FP_ + quad * 8;
#pragma unroll
        for (int kt = 0; kt < 5; kt++)
            bfrag[n][kt] = *(const bf16x8*)(wp + kt * 32);
        b1v[n] = b1[d];
    }

    // per-thread repack addresses: tile-invariant
    int roffv[8], wv[8];
    {
        const int t  = ((tid >> 5) & 3) * 8 + ((tid >> 2) & 7);
        const int kb = ((tid >> 7) & 1) * 4 + (tid & 3);
#pragma unroll
        for (int it = 0; it < 8; it++) {
            int k = it * 8 + kb;
            roffv[it] = (k < 25) ? t * 75 + 3 * k
                       : (k < 46) ? 2400 + t * 63 + 3 * (k - 25)
                                  : 4416 + t * 63 + 3 * (k - 46);
            wv[it] = ((t >> 4) * 5 + (k >> 4)) * 256
                   + (((k >> 2) & 3) * 16 + (t & 15)) * 4 + (k & 3);
        }
    }
    int roff_c = 0, w_c = 0;
    if (tid < 96) {                                     // cleanup k = 64..66
        int t = tid & 31, k = 64 + (tid >> 5);
        roff_c = 4416 + t * 63 + 3 * (k - 46);
        w_c = ((t >> 4) * 5 + (k >> 4)) * 256
            + (((k >> 2) & 3) * 16 + (t & 15)) * 4 + (k & 3);
    }

    // zero K-pad (k-pairs 67..79) in BOTH As buffers, once
    for (int i = tid; i < 832; i += 256) {
        int bufi = (i >= 416);
        int ii = i - bufi * 416;
        int t = ii & 31, kp = 67 + (ii >> 5);
        int w = ((t >> 4) * 5 + (kp >> 4)) * 256
              + (((kp >> 2) & 3) * 16 + (t & 15)) * 4 + (kp & 3);
        ((unsigned int*)As2[bufi])[w] = 0u;
    }

    auto repack = [&](int bufi) {
        const float* rw = raw[bufi];
        __bf16* A = As2[bufi];
#pragma unroll
        for (int it = 0; it < 8; it++) {
            float x = rw[roffv[it]], y = rw[roffv[it] + 1], cf = rw[roffv[it] + 2];
            bool g = cf > THR_;
            unsigned short ux = __builtin_bit_cast(unsigned short, (__bf16)(g ? x : 0.f));
            unsigned short uy = __builtin_bit_cast(unsigned short, (__bf16)(g ? y : 0.f));
            ((unsigned int*)A)[wv[it]] = (unsigned int)ux | ((unsigned int)uy << 16);
        }
        if (tid < 96) {
            float x = rw[roff_c], y = rw[roff_c + 1], cf = rw[roff_c + 2];
            bool g = cf > THR_;
            unsigned short ux = __builtin_bit_cast(unsigned short, (__bf16)(g ? x : 0.f));
            unsigned short uy = __builtin_bit_cast(unsigned short, (__bf16)(g ? y : 0.f));
            ((unsigned int*)A)[w_c] = (unsigned int)ux | ((unsigned int)uy << 16);
        }
    };

    // prologue barriers: all waves' tile-0/1 DMA + pad writes landed
    FBAR();            // vmcnt(0): every wave's DMA (tiles 0 AND 1) complete
    repack(0);
    LBAR();            // As2[0] visible to all

    // ---- main loop: one barrier per tile ----
    for (int s = 0; s < m; s++) {
        const int  bufc = s & 1;
        const bool hn   = (s + 1 < m);
        const bool hn2  = (s + 2 < m);
        int cs2 = -1;
        if (hn2) {
            cs2 = cs1 + 1 + (__ffs(mask >> (cs1 + 1)) - 1);
            stage(cs2, bufc);           // raw[s&1] free: repack(s) drained at B(s-1)
        }

        // repack(s+1) || MFMA(s): independent LDS buffers, no barrier between
        if (hn) repack(bufc ^ 1);       // raw[(s+1)&1] complete: vmcnt(0) at B(s-1)

        __builtin_amdgcn_s_setprio(1);
        f32x4 acc[2][4];
#pragma unroll
        for (int mm = 0; mm < 2; mm++)
#pragma unroll
            for (int n = 0; n < 4; n++)
                acc[mm][n] = (f32x4){0.f, 0.f, 0.f, 0.f};
#pragma unroll
        for (int kt = 0; kt < 5; kt++) {
#pragma unroll
            for (int mm = 0; mm < 2; mm++) {
                bf16x8 a = *(const bf16x8*)(As2[bufc] + (mm * 5 + kt) * 512 + lane * 8);
#pragma unroll
                for (int n = 0; n < 4; n++)
                    acc[mm][n] = __builtin_amdgcn_mfma_f32_16x16x32_bf16(a, bfrag[n][kt], acc[mm][n], 0, 0, 0);
            }
        }
        __builtin_amdgcn_s_setprio(0);

        // ---- epilogue(s): bias + relu + validity -> tile max ----
        const int bb   = (r + cs) & 63;
        const int lenb = (int)((cs < 4 ? (len01 >> (cs * 16))
                                       : (len23 >> ((cs - 4) * 16))) & 0xFFFFull);
        const int tt0  = (q + 16 * cs) * 32;
        float rmax[4] = {0.f, 0.f, 0.f, 0.f};
#pragma unroll
        for (int mm = 0; mm < 2; mm++) {
            int trow0 = tt0 + mm * 16 + quad * 4;
#pragma unroll
            for (int rr = 0; rr < 4; rr++) {
                bool valid = (trow0 + rr) < lenb;
#pragma unroll
                for (int n = 0; n < 4; n++) {
                    float v = acc[mm][n][rr] + b1v[n];
                    v = (v > 0.f) ? v : 0.f;           // forces +0, never -0
                    rmax[n] = (valid && v > rmax[n]) ? v : rmax[n];
                }
            }
        }
#pragma unroll
        for (int n = 0; n < 4; n++) {
            rmax[n] = fmaxf(rmax[n], __shfl_xor(rmax[n], 16, 64));
            rmax[n] = fmaxf(rmax[n], __shfl_xor(rmax[n], 32, 64));
        }
        float rsel = (quad == 0) ? rmax[0] : (quad == 1) ? rmax[1]
                   : (quad == 2) ? rmax[2] : rmax[3];

        // B(s): full drain (stage(s+2) + atomic(s-1)) then barrier.
        if (hn) FBAR();

        // one atomic per thread per tile, issued AFTER the barrier so the
        // vmcnt(0) above never stalls on it; it flies across iteration s+1.
        atomicMax((unsigned int*)(pooled + bb * D_ + tid),
                  __float_as_uint(rsel));              // all values >= +0

        cs = cs1; cs1 = cs2;
    }
}

__global__ void bn_classifier(const float* __restrict__ pooled,
                              const float* __restrict__ gamma,
                              const float* __restrict__ beta,
                              const float* __restrict__ Wc,
                              const float* __restrict__ bc,
                              float* __restrict__ out)
{
    __shared__ float scale_s[D_], shift_s[D_];
    const int tid = threadIdx.x;   // == d for stats
    float s = 0.f, ss = 0.f;
#pragma unroll 8
    for (int b = 0; b < B_; b++) {
        float v = pooled[b * D_ + tid];   // coalesced
        s += v; ss += v * v;
    }
    float mean = s * (1.f / B_);
    float var  = ss * (1.f / B_) - mean * mean;
    var = fmaxf(var, 0.f);
    float sc = gamma[tid] * rsqrtf(var + EPS_);
    scale_s[tid] = sc;
    shift_s[tid] = beta[tid] - mean * sc;

    const int wv = tid >> 6, ln = tid & 63;
    float wcr[4][C_];
#pragma unroll
    for (int j = 0; j < 4; j++)
#pragma unroll
        for (int c = 0; c < C_; c++)
            wcr[j][c] = Wc[(ln * 4 + j) * C_ + c];
    __syncthreads();

    for (int b = wv * 16; b < wv * 16 + 16; b++) {
        float4 v = *(const float4*)(pooled + b * D_ + ln * 4);   // coalesced
        float q[4];
        q[0] = v.x * scale_s[ln * 4 + 0] + shift_s[ln * 4 + 0];
        q[1] = v.y * scale_s[ln * 4 + 1] + shift_s[ln * 4 + 1];
        q[2] = v.z * scale_s[ln * 4 + 2] + shift_s[ln * 4 + 2];
        q[3] = v.w * scale_s[ln * 4 + 3] + shift_s[ln * 4 + 3];
        float p[C_];
#pragma unroll
        for (int c = 0; c < C_; c++) p[c] = 0.f;
#pragma unroll
        for (int j = 0; j < 4; j++)
#pragma unroll
            for (int c = 0; c < C_; c++)
                p[c] += q[j] * wcr[j][c];
#pragma unroll
        for (int c = 0; c < C_; c++) {
#pragma unroll
            for (int off = 1; off < 64; off <<= 1)
                p[c] += __shfl_xor(p[c], off, 64);
        }
        if (ln == 0) {
#pragma unroll
            for (int c = 0; c < C_; c++)
                out[b * C_ + c] = p[c] + bc[c];
        }
    }
}

extern "C" void kernel_launch(void* const* d_in, const int* in_sizes, int n_in,
                              void* d_out, int out_size, void* d_ws, size_t ws_size,
                              hipStream_t stream) {
    const float* body   = (const float*)d_in[0];
    const float* hr     = (const float*)d_in[1];
    const float* hl     = (const float*)d_in[2];
    const int*   length = (const int*)  d_in[3];
    const float* W1     = (const float*)d_in[4];
    const float* b1     = (const float*)d_in[5];
    const float* gamma  = (const float*)d_in[6];
    const float* beta   = (const float*)d_in[7];
    const float* Wc     = (const float*)d_in[8];
    const float* bc     = (const float*)d_in[9];
    float* out = (float*)d_out;

    float*  pooled = (float*)d_ws;
    __bf16* W1bf   = (__bf16*)((char*)d_ws + 65536);

    hipMemsetAsync(d_ws, 0, 65536, stream);                    // pooled = 0 (relu >= 0)
    convert_w1<<<dim3(8, 5), dim3(256), 0, stream>>>(W1, W1bf);
    fused_mlp_pool<<<dim3(NQ_ * 64), dim3(256), 0, stream>>>(body, hr, hl, length, b1, W1bf, pooled);
    bn_classifier<<<dim3(1), dim3(256), 0, stream>>>(pooled, gamma, beta, Wc, bc, out);
}